// Round 9
// baseline (237.385 us; speedup 1.0000x reference)
//
#include <hip/hip_runtime.h>
#include <math.h>

#define INPUT_DIM 256
#define N_CLASSES 100
#define MAX_DEPTH 12
#define N_NODES   4095
#define N_LEAVES  4096

#define TPB   512              // 8 waves: 6 producers + 2 consumers
#define NWAVE 8
#define PPB   6                // producer waves per block
#define CPB   2                // consumer waves per block
#define RPW   5                // rows per unit (500000 % 5 == 0)
#define TBUF  3                // producer triple buffer
#define DEPTHQ 8               // leaf ring depth (units)
#define ROWP  260              // padded row stride in floats (1040 B)
#define NF4   (N_CLASSES / 4)  // 25 float4 per output row
#define UF4   (RPW * NF4)      // 125 float4 per unit
#define NBLK  256              // 1 block per CU

#define WAITV(N) asm volatile("s_waitcnt vmcnt(" #N ")" ::: "memory")
#define WAITLGKM() asm volatile("s_waitcnt lgkmcnt(0)" ::: "memory")
#define SCHEDB() __builtin_amdgcn_sched_barrier(0)

typedef float f32x4 __attribute__((ext_vector_type(4)));

__device__ __forceinline__ void async_load16(const void* gsrc, void* ldst) {
    __builtin_amdgcn_global_load_lds(
        (const __attribute__((address_space(1))) unsigned int*)gsrc,
        (__attribute__((address_space(3))) unsigned int*)ldst, 16, 0, 0);
}

// ---------------------------------------------------------------------------
// Kernel 1: row-softmax of leaf_probabilities [4096 x 100] -> tab
// ---------------------------------------------------------------------------
__global__ __launch_bounds__(64) void softmax_rows_kernel(
    const float* __restrict__ lp, float* __restrict__ tab) {
    const int row  = blockIdx.x;
    const int lane = threadIdx.x;
    const float* src = lp + (size_t)row * N_CLASSES;

    float v0 = src[lane];
    float v1 = (lane + 64 < N_CLASSES) ? src[lane + 64] : -INFINITY;

    float m = fmaxf(v0, v1);
    #pragma unroll
    for (int off = 32; off > 0; off >>= 1) m = fmaxf(m, __shfl_xor(m, off));

    float e0 = expf(v0 - m);
    float e1 = (lane + 64 < N_CLASSES) ? expf(v1 - m) : 0.0f;
    float s = e0 + e1;
    #pragma unroll
    for (int off = 32; off > 0; off >>= 1) s += __shfl_xor(s, off);

    const float inv = 1.0f / s;
    tab[(size_t)row * N_CLASSES + lane] = e0 * inv;
    if (lane + 64 < N_CLASSES)
        tab[(size_t)row * N_CLASSES + lane + 64] = e1 * inv;
}

// ---------------------------------------------------------------------------
// Kernel 2: producer/consumer streamed traversal.
// Producers (waves 0..5): pure-read pipelines — triple-buffered 5-row LDS
//   slices via global_load_lds_dwordx4, per-wave counted vmcnt (WAITV(10)
//   steady: only DMAs in the queue), 12-level LDS chain with speculated
//   children, leaf ids published to a per-producer LDS ring (depth 8).
// Consumers (waves 6..7): each serves 3 producers round-robin — pure
//   L2-gather + coalesced nontemporal writes of out rows.
// Handshake: monotonic ready[p]/done[p] counters in LDS, volatile access,
//   lgkmcnt(0) fences, s_sleep spin. All waves co-resident -> deadlock-free.
// LDS: 6*3*5*1040 + 16380 + 4096 + ring ~= 115 KB -> 1 block/CU.
// ---------------------------------------------------------------------------
__global__ __launch_bounds__(TPB) void tree_pc_kernel(
    const float* __restrict__ x,
    const float* __restrict__ split_features,
    const float* __restrict__ split_thresholds,
    const f32x4* __restrict__ tab4,
    f32x4* __restrict__ out4,
    int batch, int nunits) {
    __shared__ float          s_rows[PPB][TBUF][RPW][ROWP];
    __shared__ float          s_thr[N_NODES];
    __shared__ unsigned char  s_feat[N_NODES + 1];
    __shared__ unsigned short s_ring[PPB][DEPTHQ][RPW + 3];  // +3 pad
    __shared__ unsigned int   s_ready[PPB];
    __shared__ unsigned int   s_done[PPB];

    const int tid  = threadIdx.x;
    const int wid  = tid >> 6;
    const int lane = tid & 63;

    // ---- init: node table + counters ----
    for (int i = tid; i < N_NODES; i += TPB) {
        s_thr[i] = split_thresholds[i];
        int f = (int)floorf(split_features[i]);
        s_feat[i] = (unsigned char)min(max(f, 0), INPUT_DIM - 1);
    }
    if (tid < PPB) { s_ready[tid] = 0u; s_done[tid] = 0u; }
    __syncthreads();          // only barrier in the kernel

    const int NP = gridDim.x * PPB;                 // total pipelines
    const int total4 = batch * NF4;

    if (wid < PPB) {
        // ================= PRODUCER =================
        const int P  = blockIdx.x * PPB + wid;
        const int nk = (P < nunits) ? ((nunits - 1 - P) / NP + 1) : 0;
        volatile unsigned int* vdone = &s_done[wid];

        auto stage = [&](int k, int slot) {
            long g = (long)P + (long)k * NP;
            if (g >= nunits) g = nunits - 1;        // dummy valid traffic
            #pragma unroll
            for (int j = 0; j < RPW; ++j) {
                long r = g * RPW + j;
                if (r >= batch) r = batch - 1;
                const float* src = x + (size_t)r * INPUT_DIM + lane * 4;
                async_load16((const void*)src, (void*)&s_rows[wid][slot][j][0]);
            }
        };

        if (nk > 0) { stage(0, 0); stage(1, 1); }

        for (int k = 0; k < nk; ++k) {
            stage(k + 2, (k + 2) % TBUF);           // prefetch distance 2
            SCHEDB();
            WAITV(10);                              // drain unit k's 5 DMAs
            SCHEDB();

            int leafv = 0;
            if (lane < RPW) {
                const float* row = &s_rows[wid][k % TBUF][lane][0];
                float t = s_thr[0];
                int   f = s_feat[0];
                int   n = 0;
                #pragma unroll
                for (int d = 0; d < MAX_DEPTH; ++d) {
                    const int l = 2 * n + 1;
                    if (d < MAX_DEPTH - 1) {
                        const float tl = s_thr[l],  tr = s_thr[l + 1];
                        const int   fl = s_feat[l], fr = s_feat[l + 1];
                        const int go = row[f] > t ? 1 : 0;
                        t = go ? tr : tl;
                        f = go ? fr : fl;
                        n = l + go;
                    } else {
                        n = l + (row[f] > t ? 1 : 0);
                    }
                }
                leafv = n - N_NODES;
            }

            // ring slot k%DEPTHQ must be consumed (unit k-DEPTHQ done)
            while ((int)*vdone < k - DEPTHQ + 1) __builtin_amdgcn_s_sleep(1);
            if (lane < RPW)
                s_ring[wid][k % DEPTHQ][lane] = (unsigned short)leafv;
            WAITLGKM();                             // data before flag
            if (lane == 0)
                *(volatile unsigned int*)&s_ready[wid] = (unsigned int)(k + 1);
        }
        WAITV(0);                                   // drain DMAs before exit
    } else {
        // ================= CONSUMER =================
        const int c = wid - PPB;                    // 0 or 1
        const int j0 = lane;                        // output f32x4 slots
        const int j1 = lane + 64;
        const int r0 = j0 / NF4,             q0 = j0 - r0 * NF4;
        const int r1c = j1 < UF4 ? j1 / NF4 : RPW - 1;
        const int q1 = j1 - (j1 / NF4) * NF4;

        int nk_[3]; int kmax = 0;
        #pragma unroll
        for (int i = 0; i < 3; ++i) {
            const int pl = 3 * c + i;
            const int P  = blockIdx.x * PPB + pl;
            nk_[i] = (P < nunits) ? ((nunits - 1 - P) / NP + 1) : 0;
            kmax = max(kmax, nk_[i]);
        }

        for (int k = 0; k < kmax; ++k) {
            #pragma unroll
            for (int i = 0; i < 3; ++i) {
                if (k >= nk_[i]) continue;
                const int pl = 3 * c + i;
                const long g = (long)(blockIdx.x * PPB + pl) + (long)k * NP;

                volatile unsigned int* vready = &s_ready[pl];
                while ((int)*vready < k + 1) __builtin_amdgcn_s_sleep(1);

                const int slot = k % DEPTHQ;
                const int lf0 = s_ring[pl][slot][r0];
                const int lf1 = s_ring[pl][slot][r1c];
                WAITLGKM();                         // reads done before ack
                if (lane == 0)
                    *(volatile unsigned int*)&s_done[pl] = (unsigned int)(k + 1);

                const long base4 = g * UF4;
                const int  maxj  = (int)min((long)UF4, (long)total4 - base4);
                if (j0 < maxj) {
                    f32x4 v = tab4[(size_t)lf0 * NF4 + q0];
                    __builtin_nontemporal_store(v, &out4[base4 + j0]);
                }
                if (j1 < maxj) {
                    f32x4 v = tab4[(size_t)lf1 * NF4 + q1];
                    __builtin_nontemporal_store(v, &out4[base4 + j1]);
                }
            }
        }
    }
}

// ---------------------------------------------------------------------------
// Fallback (ws too small / tiny batch): fully fused, per-thread softmax.
// ---------------------------------------------------------------------------
__global__ __launch_bounds__(256) void fused_kernel(
    const float* __restrict__ x,
    const float* __restrict__ split_features,
    const float* __restrict__ split_thresholds,
    const float* __restrict__ lp,
    float* __restrict__ out, int batch) {
    __shared__ float2 s_nodes[N_NODES];
    for (int i = threadIdx.x; i < N_NODES; i += blockDim.x) {
        int f = (int)floorf(split_features[i]);
        f = min(max(f, 0), INPUT_DIM - 1);
        float2 n; n.x = split_thresholds[i]; n.y = __int_as_float(f);
        s_nodes[i] = n;
    }
    __syncthreads();

    const int b = blockIdx.x * blockDim.x + threadIdx.x;
    if (b >= batch) return;

    const float* row = x + (size_t)b * INPUT_DIM;
    int node = 0;
    #pragma unroll
    for (int d = 0; d < MAX_DEPTH; ++d) {
        const float2 n = s_nodes[node];
        const float val = row[__float_as_int(n.y)];
        node = 2 * node + 1 + (val > n.x ? 1 : 0);
    }
    const int leaf = node - N_NODES;

    const float* src = lp + (size_t)leaf * N_CLASSES;
    float m = -INFINITY;
    for (int cidx = 0; cidx < N_CLASSES; ++cidx) m = fmaxf(m, src[cidx]);
    float s = 0.0f;
    float e[N_CLASSES];
    for (int cidx = 0; cidx < N_CLASSES; ++cidx) { e[cidx] = expf(src[cidx] - m); s += e[cidx]; }
    const float inv = 1.0f / s;
    float* dst = out + (size_t)b * N_CLASSES;
    for (int cidx = 0; cidx < N_CLASSES; ++cidx) dst[cidx] = e[cidx] * inv;
}

// ---------------------------------------------------------------------------
extern "C" void kernel_launch(void* const* d_in, const int* in_sizes, int n_in,
                              void* d_out, int out_size, void* d_ws, size_t ws_size,
                              hipStream_t stream) {
    const float* x  = (const float*)d_in[0];
    const float* sf = (const float*)d_in[1];
    const float* st = (const float*)d_in[2];
    const float* lp = (const float*)d_in[3];
    float* out = (float*)d_out;

    const int batch = in_sizes[0] / INPUT_DIM;

    const size_t tab_bytes = (size_t)N_LEAVES * N_CLASSES * sizeof(float); // 1.6384 MB

    if (ws_size >= tab_bytes && batch >= 4096) {
        float* tab = (float*)d_ws;

        softmax_rows_kernel<<<N_LEAVES, 64, 0, stream>>>(lp, tab);

        const int nunits = (batch + RPW - 1) / RPW;
        int nblk = (nunits + PPB - 1) / PPB;
        if (nblk > NBLK) nblk = NBLK;
        tree_pc_kernel<<<nblk, TPB, 0, stream>>>(
            x, sf, st, (const f32x4*)tab, (f32x4*)out, batch, nunits);
    } else {
        fused_kernel<<<(batch + 255) / 256, 256, 0, stream>>>(
            x, sf, st, lp, out, batch);
    }
}